// Round 3
// baseline (436.338 us; speedup 1.0000x reference)
//
#include <hip/hip_runtime.h>
#include <hip/hip_bf16.h>
#include <math.h>

#define BB 8
#define CCH 256          // channels
#define NN 2304          // H*W
#define NH 4
#define HDIM 64
#define QKV_ROWS 384
#define BN_EPS 1e-5f
#define NTILES 36        // NN / 64
// scale folded into q weights: 1/sqrt(64) * log2(e)  -> attention uses exp2
#define SLOG2E 0.18033688011112042f

typedef short bf16x8 __attribute__((ext_vector_type(8)));
typedef float f32x4 __attribute__((ext_vector_type(4)));

#if __has_builtin(__builtin_amdgcn_exp2f)
#define EXP2(x) __builtin_amdgcn_exp2f(x)
#else
#define EXP2(x) __expf((x) * 0.6931471805599453f)
#endif

__device__ __forceinline__ unsigned bfpair(float a, float b) {
    __hip_bfloat162 h = __float22bfloat162_rn(make_float2(a, b));
    return *(unsigned*)&h;
}
__device__ __forceinline__ unsigned short f2bf(float f) {
    unsigned u = __float_as_uint(f);
    u = (u + 0x7FFFu + ((u >> 16) & 1u)) >> 16;
    return (unsigned short)u;
}

// ---------------------------------------------------------------------------
// K0a: x[b][c][n] fp32 -> xT[b][n][c] bf16 (transposed, MFMA-B-ready)
// grid (36 ntiles, 4 ctiles, 8 b), 256 thr
// ---------------------------------------------------------------------------
__global__ __launch_bounds__(256) void cvt_x_k(
    const float* __restrict__ x, unsigned short* __restrict__ xT)
{
    __shared__ float sX[64][65];
    const int tid = threadIdx.x;
    const int nb = blockIdx.x * 64;
    const int cb = blockIdx.y * 64;
    const int b  = blockIdx.z;

    #pragma unroll
    for (int u = 0; u < 4; ++u) {
        int c  = (tid >> 4) + 16 * u;
        int n4 = (tid & 15) * 4;
        float4 v = *(const float4*)(x + ((size_t)(b * CCH + cb + c)) * NN + nb + n4);
        sX[c][n4+0] = v.x; sX[c][n4+1] = v.y; sX[c][n4+2] = v.z; sX[c][n4+3] = v.w;
    }
    __syncthreads();

    const int n  = tid >> 2;
    const int cg = (tid & 3) * 16;
    unsigned vals[8];
    #pragma unroll
    for (int p = 0; p < 8; ++p)
        vals[p] = bfpair(sX[cg + 2*p][n], sX[cg + 2*p + 1][n]);
    unsigned short* dst = xT + ((size_t)(b * NN + nb + n)) * CCH + cb + cg;
    *(uint4*)dst = make_uint4(vals[0], vals[1], vals[2], vals[3]);
    *(uint4*)(dst + 8) = make_uint4(vals[4], vals[5], vals[6], vals[7]);
}

// ---------------------------------------------------------------------------
// K0b: weights -> bf16. Wb[384][256] = concat(qw*SLOG2E, kw, vw); Pb = pw.
// ---------------------------------------------------------------------------
__global__ __launch_bounds__(256) void cvt_w_k(
    const float* __restrict__ qw, const float* __restrict__ kw,
    const float* __restrict__ vw, const float* __restrict__ pw,
    unsigned short* __restrict__ Wb, unsigned short* __restrict__ Pb)
{
    int idx = blockIdx.x * 256 + threadIdx.x;
    if (idx < 98304) {
        int o = idx >> 8, c = idx & 255;
        float v;
        if (o < 256)      v = qw[(size_t)o * CCH + c] * SLOG2E;
        else if (o < 320) v = kw[(size_t)(o - 256) * CCH + c];
        else              v = vw[(size_t)(o - 320) * CCH + c];
        Wb[idx] = f2bf(v);
    } else {
        int j = idx - 98304;
        if (j < 65536) Pb[j] = f2bf(pw[j]);
    }
}

// ---------------------------------------------------------------------------
// K1: qkv MFMA GEMM. out[o][n] = sum_c Wb[o][c] * xT[n][c].
// grid (36, 3, 8), 128 thr (2 waves); wave computes 64 o x 64 n.
// Epilogue -> Qt[b][n][256] (q pre-scaled), Kt[b][n][64], Vn[b][64][n], bf16.
// ---------------------------------------------------------------------------
__global__ __launch_bounds__(128) void qkv_mfma_k(
    const unsigned short* __restrict__ Wb, const unsigned short* __restrict__ xT,
    unsigned short* __restrict__ Qt, unsigned short* __restrict__ Kt,
    unsigned short* __restrict__ Vn)
{
    const int tid = threadIdx.x;
    const int wave = tid >> 6;
    const int lane = tid & 63;
    const int quad = lane >> 4;
    const int l15  = lane & 15;
    const int nb = blockIdx.x * 64;
    const int mb = blockIdx.y * 128 + wave * 64;
    const int b  = blockIdx.z;

    const unsigned short* Ab = Wb + (size_t)(mb + l15) * CCH + quad * 8;
    const unsigned short* Bb = xT + ((size_t)(b * NN + nb + l15)) * CCH + quad * 8;

    f32x4 C[4][4] = {};
    for (int k0 = 0; k0 < CCH; k0 += 32) {
        bf16x8 aA[4], bB[4];
        #pragma unroll
        for (int i = 0; i < 4; ++i) aA[i] = *(const bf16x8*)(Ab + (size_t)(16*i) * CCH + k0);
        #pragma unroll
        for (int j = 0; j < 4; ++j) bB[j] = *(const bf16x8*)(Bb + (size_t)(16*j) * CCH + k0);
        #pragma unroll
        for (int i = 0; i < 4; ++i)
            #pragma unroll
            for (int j = 0; j < 4; ++j)
                C[i][j] = __builtin_amdgcn_mfma_f32_16x16x32_bf16(aA[i], bB[j], C[i][j], 0, 0, 0);
    }

    if (mb < 256) {
        #pragma unroll
        for (int i = 0; i < 4; ++i)
            #pragma unroll
            for (int j = 0; j < 4; ++j) {
                unsigned p01 = bfpair(C[i][j][0], C[i][j][1]);
                unsigned p23 = bfpair(C[i][j][2], C[i][j][3]);
                unsigned short* p = Qt + ((size_t)(b * NN + nb + 16*j + l15)) * CCH + mb + 16*i + quad*4;
                *(unsigned*)p = p01; *(unsigned*)(p + 2) = p23;
            }
    } else if (mb < 320) {
        #pragma unroll
        for (int i = 0; i < 4; ++i)
            #pragma unroll
            for (int j = 0; j < 4; ++j) {
                unsigned p01 = bfpair(C[i][j][0], C[i][j][1]);
                unsigned p23 = bfpair(C[i][j][2], C[i][j][3]);
                unsigned short* p = Kt + ((size_t)(b * NN + nb + 16*j + l15)) * 64 + (mb - 256) + 16*i + quad*4;
                *(unsigned*)p = p01; *(unsigned*)(p + 2) = p23;
            }
    } else {
        #pragma unroll
        for (int i = 0; i < 4; ++i)
            #pragma unroll
            for (int j = 0; j < 4; ++j)
                #pragma unroll
                for (int r = 0; r < 4; ++r)
                    Vn[((size_t)(b * 64 + (mb - 320) + 16*i + quad*4 + r)) * NN + nb + 16*j + l15] =
                        f2bf(C[i][j][r]);
    }
}

// ---------------------------------------------------------------------------
// K2: MFMA attention, barrier-free. grid (36, 4 heads, 8 b), 128 thr (2 waves).
// Wave owns 32 queries; P round-trip through wave-private LDS; K/V fragments
// straight from global (L1/L2); K-frags double-buffered. Max-free softmax via
// exp2 (scale*log2e folded into q weights). Output bf16 [b][n][256].
// ---------------------------------------------------------------------------
__global__ __launch_bounds__(128) void attn_k(
    const unsigned short* __restrict__ Qt,  // [B][N][256]
    const unsigned short* __restrict__ Kt,  // [B][N][64]
    const unsigned short* __restrict__ Vn,  // [B][64][N]
    unsigned short* __restrict__ Ao)        // [B][N][256]
{
    __shared__ unsigned short sP[2][32][72];   // wave-private P, pitch 72 (16B-mult)
    const int tid  = threadIdx.x;
    const int wave = tid >> 6;
    const int lane = tid & 63;
    const int quad = lane >> 4;
    const int l15  = lane & 15;
    const int nb   = blockIdx.x * 64;
    const int head = blockIdx.y;
    const int b    = blockIdx.z;
    const int qoff = wave * 32;

    unsigned short* sPw = &sP[wave][0][0];

    // Q fragments, held in registers: A[m = l15][k = quad*8 + j]
    bf16x8 aQ[2][2];
    const unsigned short* QtB = Qt + ((size_t)(b * NN + nb + qoff + l15)) * CCH + head * 64 + quad * 8;
    #pragma unroll
    for (int i = 0; i < 2; ++i)
        #pragma unroll
        for (int s = 0; s < 2; ++s)
            aQ[i][s] = *(const bf16x8*)(QtB + (size_t)(16*i) * CCH + s * 32);

    const unsigned short* KtB = Kt + ((size_t)(b * NN + l15)) * 64 + quad * 8;
    const unsigned short* VnB = Vn + ((size_t)(b * 64 + l15)) * NN + quad * 8;

    bf16x8 bK[2][4][2];   // double-buffered K fragments
    bf16x8 bV[4][2];
    #pragma unroll
    for (int j = 0; j < 4; ++j)
        #pragma unroll
        for (int s = 0; s < 2; ++s)
            bK[0][j][s] = *(const bf16x8*)(KtB + (size_t)(16*j) * 64 + s * 32);

    f32x4 O[2][4] = {};
    float lacc[2][4] = {};

    for (int t = 0; t < NTILES; ++t) {
        const int cur = t & 1;
        const int m0  = t * 64;
        const int m0n = (t + 1 < NTILES) ? (t + 1) * 64 : 0;

        // V frags for this tile (used after S phase — latency covered)
        #pragma unroll
        for (int jd = 0; jd < 4; ++jd)
            #pragma unroll
            for (int s = 0; s < 2; ++s)
                bV[jd][s] = *(const bf16x8*)(VnB + (size_t)(16*jd) * NN + m0 + s * 32);
        // prefetch next tile's K frags
        #pragma unroll
        for (int j = 0; j < 4; ++j)
            #pragma unroll
            for (int s = 0; s < 2; ++s)
                bK[cur ^ 1][j][s] = *(const bf16x8*)(KtB + (size_t)(m0n + 16*j) * 64 + s * 32);

        // S = Q . K^T (pre-scaled by scale*log2e)
        f32x4 C[2][4] = {};
        #pragma unroll
        for (int s = 0; s < 2; ++s)
            #pragma unroll
            for (int j = 0; j < 4; ++j) {
                C[0][j] = __builtin_amdgcn_mfma_f32_16x16x32_bf16(aQ[0][s], bK[cur][j][s], C[0][j], 0, 0, 0);
                C[1][j] = __builtin_amdgcn_mfma_f32_16x16x32_bf16(aQ[1][s], bK[cur][j][s], C[1][j], 0, 0, 0);
            }

        // P = exp2(S); pack to bf16; store to wave-private LDS (A-layout rows)
        #pragma unroll
        for (int i = 0; i < 2; ++i)
            #pragma unroll
            for (int j = 0; j < 4; ++j) {
                float p0 = EXP2(C[i][j][0]);
                float p1 = EXP2(C[i][j][1]);
                float p2 = EXP2(C[i][j][2]);
                float p3 = EXP2(C[i][j][3]);
                lacc[i][0] += p0; lacc[i][1] += p1; lacc[i][2] += p2; lacc[i][3] += p3;
                unsigned p01 = bfpair(p0, p1);
                unsigned p23 = bfpair(p2, p3);
                unsigned short* bp = sPw + (16*i + quad*4) * 72 + 16*j + l15;
                bp[0]   = (unsigned short)p01;
                bp[72]  = (unsigned short)(p01 >> 16);
                bp[144] = (unsigned short)p23;
                bp[216] = (unsigned short)(p23 >> 16);
            }

        // O += P . V^T  (same-wave LDS write->read: ordered, no barrier)
        #pragma unroll
        for (int s = 0; s < 2; ++s) {
            bf16x8 aP0 = *(const bf16x8*)(sPw + l15 * 72 + s * 32 + quad * 8);
            bf16x8 aP1 = *(const bf16x8*)(sPw + (16 + l15) * 72 + s * 32 + quad * 8);
            #pragma unroll
            for (int jd = 0; jd < 4; ++jd) {
                O[0][jd] = __builtin_amdgcn_mfma_f32_16x16x32_bf16(aP0, bV[jd][s], O[0][jd], 0, 0, 0);
                O[1][jd] = __builtin_amdgcn_mfma_f32_16x16x32_bf16(aP1, bV[jd][s], O[1][jd], 0, 0, 0);
            }
        }
    }

    // softmax denominators (sum across the 16 l15 lanes of each quad row-group)
    float rinv[2][4];
    #pragma unroll
    for (int i = 0; i < 2; ++i)
        #pragma unroll
        for (int r = 0; r < 4; ++r) {
            float s = lacc[i][r];
            s += __shfl_xor(s, 1);
            s += __shfl_xor(s, 2);
            s += __shfl_xor(s, 4);
            s += __shfl_xor(s, 8);
            rinv[i][r] = 1.0f / s;
        }

    // write O as bf16 into proj-B-ready layout Ao[b][n][head*64 + d]
    #pragma unroll
    for (int i = 0; i < 2; ++i)
        #pragma unroll
        for (int jd = 0; jd < 4; ++jd)
            #pragma unroll
            for (int rp = 0; rp < 4; rp += 2) {
                float v0 = O[i][jd][rp]     * rinv[i][rp];
                float v1 = O[i][jd][rp + 1] * rinv[i][rp + 1];
                unsigned pp = bfpair(v0, v1);
                size_t base = ((size_t)(b * NN + nb + qoff + 16*i + quad*4 + rp)) * CCH
                              + head * 64 + 16*jd + l15;
                Ao[base]       = (unsigned short)pp;
                Ao[base + CCH] = (unsigned short)(pp >> 16);
            }
}

// ---------------------------------------------------------------------------
// K3: proj MFMA GEMM. proj[b][c][n] = sum_o Pb[c][o] * Ao[b][n][o] + pb[c]
// grid (36, 2, 8), 128 thr (2 waves); fp32 output.
// ---------------------------------------------------------------------------
__global__ __launch_bounds__(128) void proj_mfma_k(
    const unsigned short* __restrict__ Pb, const unsigned short* __restrict__ Ao,
    const float* __restrict__ pb, float* __restrict__ proj)
{
    const int tid = threadIdx.x;
    const int wave = tid >> 6;
    const int lane = tid & 63;
    const int quad = lane >> 4;
    const int l15  = lane & 15;
    const int nb = blockIdx.x * 64;
    const int mb = blockIdx.y * 128 + wave * 64;
    const int b  = blockIdx.z;

    const unsigned short* Ab = Pb + (size_t)(mb + l15) * CCH + quad * 8;
    const unsigned short* Bb = Ao + ((size_t)(b * NN + nb + l15)) * CCH + quad * 8;

    f32x4 C[4][4] = {};
    for (int k0 = 0; k0 < CCH; k0 += 32) {
        bf16x8 aA[4], bB[4];
        #pragma unroll
        for (int i = 0; i < 4; ++i) aA[i] = *(const bf16x8*)(Ab + (size_t)(16*i) * CCH + k0);
        #pragma unroll
        for (int j = 0; j < 4; ++j) bB[j] = *(const bf16x8*)(Bb + (size_t)(16*j) * CCH + k0);
        #pragma unroll
        for (int i = 0; i < 4; ++i)
            #pragma unroll
            for (int j = 0; j < 4; ++j)
                C[i][j] = __builtin_amdgcn_mfma_f32_16x16x32_bf16(aA[i], bB[j], C[i][j], 0, 0, 0);
    }

    float pbv[4][4];
    #pragma unroll
    for (int i = 0; i < 4; ++i)
        #pragma unroll
        for (int r = 0; r < 4; ++r)
            pbv[i][r] = pb[mb + 16*i + quad*4 + r];

    #pragma unroll
    for (int i = 0; i < 4; ++i)
        #pragma unroll
        for (int j = 0; j < 4; ++j)
            #pragma unroll
            for (int r = 0; r < 4; ++r)
                proj[((size_t)(b * CCH + mb + 16*i + quad*4 + r)) * NN + nb + 16*j + l15] =
                    C[i][j][r] + pbv[i][r];
}

// ---------------------------------------------------------------------------
// K4: per-channel batch stats -> scale/shift
// ---------------------------------------------------------------------------
__global__ __launch_bounds__(256) void bn_stats_k(
    const float* __restrict__ proj, const float* __restrict__ gamma,
    const float* __restrict__ beta, float* __restrict__ stats)
{
    const int c = blockIdx.x;
    const int tid = threadIdx.x;
    float s = 0.f, s2 = 0.f;
    for (int b = 0; b < BB; ++b) {
        const float* p = proj + ((size_t)b * CCH + c) * NN;
        for (int n = tid * 4; n < NN; n += 1024) {
            float4 v = *(const float4*)(p + n);
            s  += v.x + v.y + v.z + v.w;
            s2 += v.x*v.x + v.y*v.y + v.z*v.z + v.w*v.w;
        }
    }
    __shared__ float rs[256], rs2[256];
    rs[tid] = s; rs2[tid] = s2;
    __syncthreads();
    for (int off = 128; off > 0; off >>= 1) {
        if (tid < off) { rs[tid] += rs[tid + off]; rs2[tid] += rs2[tid + off]; }
        __syncthreads();
    }
    if (tid == 0) {
        const float inv_n = 1.0f / (float)(BB * NN);
        float mean = rs[0] * inv_n;
        float var  = rs2[0] * inv_n - mean * mean;
        float sc = gamma[c] * rsqrtf(var + BN_EPS);
        stats[c] = sc;
        stats[CCH + c] = beta[c] - mean * sc;
    }
}

// ---------------------------------------------------------------------------
// K5: out = scale[c]*proj + shift[c] + x
// ---------------------------------------------------------------------------
__global__ __launch_bounds__(256) void bn_apply_k(
    const float* __restrict__ proj, const float* __restrict__ x,
    const float* __restrict__ stats, float* __restrict__ out)
{
    size_t idx = ((size_t)blockIdx.x * 256 + threadIdx.x) * 4;
    const size_t total = (size_t)BB * CCH * NN;
    if (idx >= total) return;
    int c = (int)((idx / NN) % CCH);
    float sc = stats[c], sh = stats[CCH + c];
    float4 p  = *(const float4*)(proj + idx);
    float4 xv = *(const float4*)(x + idx);
    float4 r;
    r.x = sc * p.x + sh + xv.x;
    r.y = sc * p.y + sh + xv.y;
    r.z = sc * p.z + sh + xv.z;
    r.w = sc * p.w + sh + xv.w;
    *(float4*)(out + idx) = r;
}

extern "C" void kernel_launch(void* const* d_in, const int* in_sizes, int n_in,
                              void* d_out, int out_size, void* d_ws, size_t ws_size,
                              hipStream_t stream)
{
    const float* x     = (const float*)d_in[0];
    const float* qw    = (const float*)d_in[1];
    const float* kw    = (const float*)d_in[2];
    const float* vw    = (const float*)d_in[3];
    const float* pw    = (const float*)d_in[4];
    const float* pb    = (const float*)d_in[5];
    const float* gamma = (const float*)d_in[6];
    const float* beta  = (const float*)d_in[7];
    float* out = (float*)d_out;

    char* ws = (char*)d_ws;
    // Layout (bytes). Ao overlays xT (dead after K1); proj overlays Qt/Kt/Vn
    // (dead after K2) + 4.8 MB tail. Total ~28.6 MB.
    unsigned short* xT = (unsigned short*)ws;                       //  9,437,184
    unsigned short* Ao = (unsigned short*)ws;                       //  9,437,184 (overlay)
    unsigned short* Wb = (unsigned short*)(ws + 9437184);           //    196,608
    unsigned short* Pb = (unsigned short*)(ws + 9633792);           //    131,072
    unsigned short* Qt = (unsigned short*)(ws + 9764864);           //  9,437,184
    unsigned short* Kt = (unsigned short*)(ws + 19202048);          //  2,359,296
    unsigned short* Vn = (unsigned short*)(ws + 21561344);          //  2,359,296
    float* proj  = (float*)(ws + 9764864);                          // 18,874,368 (overlay)
    float* stats = (float*)(ws + 28639232);                         //      2,048

    cvt_w_k<<<640, 256, 0, stream>>>(qw, kw, vw, pw, Wb, Pb);

    dim3 g0(NN / 64, CCH / 64, BB);
    cvt_x_k<<<g0, 256, 0, stream>>>(x, xT);

    dim3 g1(NN / 64, 3, BB);
    qkv_mfma_k<<<g1, 128, 0, stream>>>(Wb, xT, Qt, Kt, Vn);

    dim3 g2(NN / 64, NH, BB);
    attn_k<<<g2, 128, 0, stream>>>(Qt, Kt, Vn, Ao);

    dim3 g3(NN / 64, 2, BB);
    proj_mfma_k<<<g3, 128, 0, stream>>>(Pb, Ao, pb, proj);

    bn_stats_k<<<CCH, 256, 0, stream>>>(proj, gamma, beta, stats);

    int total4 = BB * CCH * NN / 4;
    bn_apply_k<<<(total4 + 255) / 256, 256, 0, stream>>>(proj, x, stats, out);
}

// Round 4
// 224.583 us; speedup vs baseline: 1.9429x; 1.9429x over previous
//
#include <hip/hip_runtime.h>
#include <hip/hip_bf16.h>
#include <math.h>

#define BB 8
#define CCH 256          // channels
#define NN 2304          // H*W
#define NH 4
#define HDIM 64
#define QKV_ROWS 384
#define BN_EPS 1e-5f
#define NTILES 36        // NN / 64
// scale folded into q weights: 1/sqrt(64) * log2(e)  -> attention uses exp2
#define SLOG2E 0.18033688011112042f

typedef short bf16x8 __attribute__((ext_vector_type(8)));
typedef float f32x4 __attribute__((ext_vector_type(4)));

#if __has_builtin(__builtin_amdgcn_exp2f)
#define EXP2(x) __builtin_amdgcn_exp2f(x)
#else
#define EXP2(x) __expf((x) * 0.6931471805599453f)
#endif

__device__ __forceinline__ unsigned bfpair(float a, float b) {
    __hip_bfloat162 h = __float22bfloat162_rn(make_float2(a, b));
    return *(unsigned*)&h;
}
__device__ __forceinline__ unsigned short f2bf(float f) {
    unsigned u = __float_as_uint(f);
    u = (u + 0x7FFFu + ((u >> 16) & 1u)) >> 16;
    return (unsigned short)u;
}

// ---------------------------------------------------------------------------
// K0a: x[b][c][n] fp32 -> xT[b][n][c] bf16.  grid (8 b, 36 ntile, 4 ctile)
// ---------------------------------------------------------------------------
__global__ __launch_bounds__(256) void cvt_x_k(
    const float* __restrict__ x, unsigned short* __restrict__ xT)
{
    __shared__ float sX[64][65];
    const int tid = threadIdx.x;
    const int b  = blockIdx.x;
    const int nb = blockIdx.y * 64;
    const int cb = blockIdx.z * 64;

    #pragma unroll
    for (int u = 0; u < 4; ++u) {
        int c  = (tid >> 4) + 16 * u;
        int n4 = (tid & 15) * 4;
        float4 v = *(const float4*)(x + ((size_t)(b * CCH + cb + c)) * NN + nb + n4);
        sX[c][n4+0] = v.x; sX[c][n4+1] = v.y; sX[c][n4+2] = v.z; sX[c][n4+3] = v.w;
    }
    __syncthreads();

    const int n  = tid >> 2;
    const int cg = (tid & 3) * 16;
    unsigned vals[8];
    #pragma unroll
    for (int p = 0; p < 8; ++p)
        vals[p] = bfpair(sX[cg + 2*p][n], sX[cg + 2*p + 1][n]);
    unsigned short* dst = xT + ((size_t)(b * NN + nb + n)) * CCH + cb + cg;
    *(uint4*)dst = make_uint4(vals[0], vals[1], vals[2], vals[3]);
    *(uint4*)(dst + 8) = make_uint4(vals[4], vals[5], vals[6], vals[7]);
}

// ---------------------------------------------------------------------------
// K0b: weights -> bf16. Wb[384][256] = concat(qw*SLOG2E, kw, vw); Pb = pw.
// ---------------------------------------------------------------------------
__global__ __launch_bounds__(256) void cvt_w_k(
    const float* __restrict__ qw, const float* __restrict__ kw,
    const float* __restrict__ vw, const float* __restrict__ pw,
    unsigned short* __restrict__ Wb, unsigned short* __restrict__ Pb)
{
    int idx = blockIdx.x * 256 + threadIdx.x;
    if (idx < 98304) {
        int o = idx >> 8, c = idx & 255;
        float v;
        if (o < 256)      v = qw[(size_t)o * CCH + c] * SLOG2E;
        else if (o < 320) v = kw[(size_t)(o - 256) * CCH + c];
        else              v = vw[(size_t)(o - 320) * CCH + c];
        Wb[idx] = f2bf(v);
    } else {
        int j = idx - 98304;
        if (j < 65536) Pb[j] = f2bf(pw[j]);
    }
}

// ---------------------------------------------------------------------------
// K1: qkv MFMA GEMM. grid (8 b, 36 ntile, 3 otile), 128 thr (2 waves).
// Wave = 64 o x 64 n. Epilogue transposes through per-wave LDS so all global
// stores are uint4 (16B) coalesced:
//   Qt[b][n][256] (q pre-scaled), Kt[b][n][64], Vn[b][64][n], all bf16.
// ---------------------------------------------------------------------------
__global__ __launch_bounds__(128) void qkv_mfma_k(
    const unsigned short* __restrict__ Wb, const unsigned short* __restrict__ xT,
    unsigned short* __restrict__ Qt, unsigned short* __restrict__ Kt,
    unsigned short* __restrict__ Vn)
{
    __shared__ unsigned short sE[2][64 * 72];   // per-wave transpose buffer
    const int tid = threadIdx.x;
    const int wave = tid >> 6;
    const int lane = tid & 63;
    const int quad = lane >> 4;
    const int l15  = lane & 15;
    const int b  = blockIdx.x;
    const int nb = blockIdx.y * 64;
    const int mb = blockIdx.z * 128 + wave * 64;

    const unsigned short* Ab = Wb + (size_t)(mb + l15) * CCH + quad * 8;
    const unsigned short* Bb = xT + ((size_t)(b * NN + nb + l15)) * CCH + quad * 8;

    f32x4 C[4][4] = {};
    for (int k0 = 0; k0 < CCH; k0 += 32) {
        bf16x8 aA[4], bB[4];
        #pragma unroll
        for (int i = 0; i < 4; ++i) aA[i] = *(const bf16x8*)(Ab + (size_t)(16*i) * CCH + k0);
        #pragma unroll
        for (int j = 0; j < 4; ++j) bB[j] = *(const bf16x8*)(Bb + (size_t)(16*j) * CCH + k0);
        #pragma unroll
        for (int i = 0; i < 4; ++i)
            #pragma unroll
            for (int j = 0; j < 4; ++j)
                C[i][j] = __builtin_amdgcn_mfma_f32_16x16x32_bf16(aA[i], bB[j], C[i][j], 0, 0, 0);
    }

    unsigned short* sEw = &sE[wave][0];
    if (mb < 320) {
        // Q or K: transpose to [n][o] rows (o consecutive = reg pairs -> b32)
        #pragma unroll
        for (int i = 0; i < 4; ++i)
            #pragma unroll
            for (int j = 0; j < 4; ++j) {
                unsigned p01 = bfpair(C[i][j][0], C[i][j][1]);
                unsigned p23 = bfpair(C[i][j][2], C[i][j][3]);
                unsigned short* p = sEw + (16*j + l15) * 72 + 16*i + quad*4;
                *(unsigned*)p = p01;
                *(unsigned*)(p + 2) = p23;
            }
        // same-wave LDS write->read ordering; no barrier needed
        if (mb < 256) {
            #pragma unroll
            for (int it = 0; it < 8; ++it) {
                int flat = lane + 64 * it;
                int row = flat >> 3;            // n local
                int o8  = (flat & 7) * 8;
                uint4 v = *(const uint4*)(sEw + row * 72 + o8);
                *(uint4*)(Qt + ((size_t)(b * NN + nb + row)) * CCH + mb + o8) = v;
            }
        } else {
            #pragma unroll
            for (int it = 0; it < 8; ++it) {
                int flat = lane + 64 * it;
                int row = flat >> 3;
                int o8  = (flat & 7) * 8;
                uint4 v = *(const uint4*)(sEw + row * 72 + o8);
                *(uint4*)(Kt + ((size_t)(b * NN + nb + row)) * 64 + o8) = v;
            }
        }
    } else {
        // V: keep [d][n] rows (n consecutive = lanes) -> b16 LDS scatter, then
        // coalesced uint4 global stores.
        #pragma unroll
        for (int i = 0; i < 4; ++i)
            #pragma unroll
            for (int j = 0; j < 4; ++j) {
                unsigned p01 = bfpair(C[i][j][0], C[i][j][1]);
                unsigned p23 = bfpair(C[i][j][2], C[i][j][3]);
                unsigned short* p = sEw + (16*i + quad*4) * 72 + 16*j + l15;
                p[0]   = (unsigned short)p01;
                p[72]  = (unsigned short)(p01 >> 16);
                p[144] = (unsigned short)p23;
                p[216] = (unsigned short)(p23 >> 16);
            }
        #pragma unroll
        for (int it = 0; it < 8; ++it) {
            int flat = lane + 64 * it;
            int row = flat >> 3;                // d local
            int n8  = (flat & 7) * 8;
            uint4 v = *(const uint4*)(sEw + row * 72 + n8);
            *(uint4*)(Vn + ((size_t)(b * 64 + (mb - 320) + row)) * NN + nb + n8) = v;
        }
    }
}

// ---------------------------------------------------------------------------
// K2: MFMA attention. grid (8 b, 36 qtiles, 2 head-pairs), 256 thr (4 waves).
// Wave w: head = z*2 + (w>>1), queries qoff = (w&1)*32. K/V staged in LDS
// (shared by all 4 waves), register-prefetched. Max-free softmax via exp2
// (scale*log2e folded into q weights). P LDS round-trip per verified pattern.
// Epilogue: LDS transpose -> coalesced uint4 bf16 stores Ao[b][n][256].
// ---------------------------------------------------------------------------
__global__ __launch_bounds__(256) void attn_k(
    const unsigned short* __restrict__ Qt,  // [B][N][256]
    const unsigned short* __restrict__ Kt,  // [B][N][64]
    const unsigned short* __restrict__ Vn,  // [B][64][N]
    unsigned short* __restrict__ Ao)        // [B][N][256]
{
    __shared__ __align__(16) char smem[36864];
    unsigned short* sK = (unsigned short*)smem;            // [64][72]
    unsigned short* sV = (unsigned short*)(smem + 9216);   // [64][72]
    unsigned short* sP = (unsigned short*)(smem + 18432);  // [2][64][72]
    unsigned short* sT = (unsigned short*)smem;            // [64][136] (epilogue overlay)

    const int tid  = threadIdx.x;
    const int wave = tid >> 6;
    const int lane = tid & 63;
    const int quad = lane >> 4;
    const int l15  = lane & 15;
    const int hloc = wave >> 1;
    const int qoff = (wave & 1) * 32;
    const int b    = blockIdx.x;
    const int nb   = blockIdx.y * 64;
    const int head = blockIdx.z * 2 + hloc;

    unsigned short* sPh = sP + hloc * 64 * 72;

    // Q fragments in registers: A[m = l15][k = quad*8 + j]
    bf16x8 aQ[2][2];
    const unsigned short* QtB = Qt + ((size_t)(b * NN + nb + qoff + l15)) * CCH + head * 64 + quad * 8;
    #pragma unroll
    for (int i = 0; i < 2; ++i)
        #pragma unroll
        for (int s = 0; s < 2; ++s)
            aQ[i][s] = *(const bf16x8*)(QtB + (size_t)(16*i) * CCH + s * 32);

    // staging indices (256 threads cover one 64x64 bf16 tile in 2 steps)
    const int srow = tid >> 3;          // 0..31 (+32 on u=1)
    const int sch  = (tid & 7) * 8;

    // tile-0 prefetch
    bf16x8 pK[2], pV[2];
    #pragma unroll
    for (int u = 0; u < 2; ++u) {
        int row = srow + 32 * u;
        pK[u] = *(const bf16x8*)(Kt + ((size_t)(b * NN + row)) * 64 + sch);
        pV[u] = *(const bf16x8*)(Vn + ((size_t)(b * 64 + row)) * NN + sch);
    }

    f32x4 O[2][4] = {};
    float lacc[2][4] = {};

    for (int t = 0; t < NTILES; ++t) {
        __syncthreads();   // previous tile's LDS reads complete
        #pragma unroll
        for (int u = 0; u < 2; ++u) {
            int row = srow + 32 * u;
            *(bf16x8*)(sK + row * 72 + sch) = pK[u];
            *(bf16x8*)(sV + row * 72 + sch) = pV[u];
        }
        __syncthreads();

        if (t + 1 < NTILES) {
            const int m0n = (t + 1) * 64;
            #pragma unroll
            for (int u = 0; u < 2; ++u) {
                int row = srow + 32 * u;
                pK[u] = *(const bf16x8*)(Kt + ((size_t)(b * NN + m0n + row)) * 64 + sch);
                pV[u] = *(const bf16x8*)(Vn + ((size_t)(b * 64 + row)) * NN + m0n + sch);
            }
        }

        // S = Q . K^T
        f32x4 C[2][4] = {};
        #pragma unroll
        for (int s = 0; s < 2; ++s)
            #pragma unroll
            for (int j = 0; j < 4; ++j) {
                bf16x8 bK = *(const bf16x8*)(sK + (16*j + l15) * 72 + s * 32 + quad * 8);
                C[0][j] = __builtin_amdgcn_mfma_f32_16x16x32_bf16(aQ[0][s], bK, C[0][j], 0, 0, 0);
                C[1][j] = __builtin_amdgcn_mfma_f32_16x16x32_bf16(aQ[1][s], bK, C[1][j], 0, 0, 0);
            }

        // P = exp2(S); pack bf16 (hw cvt); store to own rows of sPh
        #pragma unroll
        for (int i = 0; i < 2; ++i)
            #pragma unroll
            for (int j = 0; j < 4; ++j) {
                float p0 = EXP2(C[i][j][0]);
                float p1 = EXP2(C[i][j][1]);
                float p2 = EXP2(C[i][j][2]);
                float p3 = EXP2(C[i][j][3]);
                lacc[i][0] += p0; lacc[i][1] += p1; lacc[i][2] += p2; lacc[i][3] += p3;
                unsigned p01 = bfpair(p0, p1);
                unsigned p23 = bfpair(p2, p3);
                unsigned short* bp = sPh + (qoff + 16*i + quad*4) * 72 + 16*j + l15;
                bp[0]   = (unsigned short)p01;
                bp[72]  = (unsigned short)(p01 >> 16);
                bp[144] = (unsigned short)p23;
                bp[216] = (unsigned short)(p23 >> 16);
            }

        // O += P . V^T  (same-wave LDS write->read: ordered, no barrier)
        #pragma unroll
        for (int s = 0; s < 2; ++s) {
            bf16x8 aP0 = *(const bf16x8*)(sPh + (qoff +  0 + l15) * 72 + s * 32 + quad * 8);
            bf16x8 aP1 = *(const bf16x8*)(sPh + (qoff + 16 + l15) * 72 + s * 32 + quad * 8);
            #pragma unroll
            for (int jd = 0; jd < 4; ++jd) {
                bf16x8 bV = *(const bf16x8*)(sV + (16*jd + l15) * 72 + s * 32 + quad * 8);
                O[0][jd] = __builtin_amdgcn_mfma_f32_16x16x32_bf16(aP0, bV, O[0][jd], 0, 0, 0);
                O[1][jd] = __builtin_amdgcn_mfma_f32_16x16x32_bf16(aP1, bV, O[1][jd], 0, 0, 0);
            }
        }
    }

    // softmax denominators: sum across the 16 key-lanes (l15) per row
    float rinv[2][4];
    #pragma unroll
    for (int i = 0; i < 2; ++i)
        #pragma unroll
        for (int r = 0; r < 4; ++r) {
            float s = lacc[i][r];
            s += __shfl_xor(s, 1);
            s += __shfl_xor(s, 2);
            s += __shfl_xor(s, 4);
            s += __shfl_xor(s, 8);
            rinv[i][r] = 1.0f / s;
        }

    __syncthreads();   // all waves done with sK/sV before sT overlay
    // sT[n_local][c_local] : n = qoff+16i+quad*4+r, c = hloc*64 + 16jd + l15
    #pragma unroll
    for (int i = 0; i < 2; ++i)
        #pragma unroll
        for (int jd = 0; jd < 4; ++jd)
            #pragma unroll
            for (int r = 0; r < 4; ++r)
                sT[(qoff + 16*i + quad*4 + r) * 136 + hloc * 64 + 16*jd + l15] =
                    f2bf(O[i][jd][r] * rinv[i][r]);
    __syncthreads();

    // coalesced writeout: 64 rows x 128 channels, uint4 per lane
    #pragma unroll
    for (int it = 0; it < 4; ++it) {
        int flat = tid + 256 * it;          // 0..1023 16B-chunks
        int row = flat >> 4;
        int c8  = (flat & 15) * 8;
        uint4 v = *(const uint4*)(sT + row * 136 + c8);
        *(uint4*)(Ao + ((size_t)(b * NN + nb + row)) * CCH + blockIdx.z * 128 + c8) = v;
    }
}

// ---------------------------------------------------------------------------
// K3: proj MFMA GEMM. proj[b][c][n] = sum_o Pb[c][o] * Ao[b][n][o] + pb[c]
// grid (8 b, 36 ntile, 2 ctile), 128 thr (2 waves); fp32 out via LDS
// transpose -> float4 coalesced stores.
// ---------------------------------------------------------------------------
__global__ __launch_bounds__(128) void proj_mfma_k(
    const unsigned short* __restrict__ Pb, const unsigned short* __restrict__ Ao,
    const float* __restrict__ pb, float* __restrict__ proj)
{
    __shared__ float sF[2][64 * 68];
    const int tid = threadIdx.x;
    const int wave = tid >> 6;
    const int lane = tid & 63;
    const int quad = lane >> 4;
    const int l15  = lane & 15;
    const int b  = blockIdx.x;
    const int nb = blockIdx.y * 64;
    const int mb = blockIdx.z * 128 + wave * 64;

    const unsigned short* Ab = Pb + (size_t)(mb + l15) * CCH + quad * 8;
    const unsigned short* Bb = Ao + ((size_t)(b * NN + nb + l15)) * CCH + quad * 8;

    f32x4 C[4][4] = {};
    for (int k0 = 0; k0 < CCH; k0 += 32) {
        bf16x8 aA[4], bB[4];
        #pragma unroll
        for (int i = 0; i < 4; ++i) aA[i] = *(const bf16x8*)(Ab + (size_t)(16*i) * CCH + k0);
        #pragma unroll
        for (int j = 0; j < 4; ++j) bB[j] = *(const bf16x8*)(Bb + (size_t)(16*j) * CCH + k0);
        #pragma unroll
        for (int i = 0; i < 4; ++i)
            #pragma unroll
            for (int j = 0; j < 4; ++j)
                C[i][j] = __builtin_amdgcn_mfma_f32_16x16x32_bf16(aA[i], bB[j], C[i][j], 0, 0, 0);
    }

    float* sFw = &sF[wave][0];
    #pragma unroll
    for (int i = 0; i < 4; ++i)
        #pragma unroll
        for (int r = 0; r < 4; ++r) {
            float bias = pb[mb + 16*i + quad*4 + r];
            #pragma unroll
            for (int j = 0; j < 4; ++j)
                sFw[(16*i + quad*4 + r) * 68 + 16*j + l15] = C[i][j][r] + bias;
        }
    // same-wave LDS ordering; no barrier needed
    #pragma unroll
    for (int it = 0; it < 16; ++it) {
        int flat = lane + 64 * it;
        int row = flat >> 4;                 // c local
        int ch  = (flat & 15) * 4;           // n chunk
        f32x4 v = *(const f32x4*)(sFw + row * 68 + ch);
        *(f32x4*)(proj + ((size_t)(b * CCH + mb + row)) * NN + nb + ch) = v;
    }
}

// ---------------------------------------------------------------------------
// K4: per-channel batch stats -> scale/shift
// ---------------------------------------------------------------------------
__global__ __launch_bounds__(256) void bn_stats_k(
    const float* __restrict__ proj, const float* __restrict__ gamma,
    const float* __restrict__ beta, float* __restrict__ stats)
{
    const int c = blockIdx.x;
    const int tid = threadIdx.x;
    float s = 0.f, s2 = 0.f;
    for (int b = 0; b < BB; ++b) {
        const float* p = proj + ((size_t)b * CCH + c) * NN;
        for (int n = tid * 4; n < NN; n += 1024) {
            float4 v = *(const float4*)(p + n);
            s  += v.x + v.y + v.z + v.w;
            s2 += v.x*v.x + v.y*v.y + v.z*v.z + v.w*v.w;
        }
    }
    __shared__ float rs[256], rs2[256];
    rs[tid] = s; rs2[tid] = s2;
    __syncthreads();
    for (int off = 128; off > 0; off >>= 1) {
        if (tid < off) { rs[tid] += rs[tid + off]; rs2[tid] += rs2[tid + off]; }
        __syncthreads();
    }
    if (tid == 0) {
        const float inv_n = 1.0f / (float)(BB * NN);
        float mean = rs[0] * inv_n;
        float var  = rs2[0] * inv_n - mean * mean;
        float sc = gamma[c] * rsqrtf(var + BN_EPS);
        stats[c] = sc;
        stats[CCH + c] = beta[c] - mean * sc;
    }
}

// ---------------------------------------------------------------------------
// K5: out = scale[c]*proj + shift[c] + x
// ---------------------------------------------------------------------------
__global__ __launch_bounds__(256) void bn_apply_k(
    const float* __restrict__ proj, const float* __restrict__ x,
    const float* __restrict__ stats, float* __restrict__ out)
{
    size_t idx = ((size_t)blockIdx.x * 256 + threadIdx.x) * 4;
    const size_t total = (size_t)BB * CCH * NN;
    if (idx >= total) return;
    int c = (int)((idx / NN) % CCH);
    float sc = stats[c], sh = stats[CCH + c];
    float4 p  = *(const float4*)(proj + idx);
    float4 xv = *(const float4*)(x + idx);
    float4 r;
    r.x = sc * p.x + sh + xv.x;
    r.y = sc * p.y + sh + xv.y;
    r.z = sc * p.z + sh + xv.z;
    r.w = sc * p.w + sh + xv.w;
    *(float4*)(out + idx) = r;
}

extern "C" void kernel_launch(void* const* d_in, const int* in_sizes, int n_in,
                              void* d_out, int out_size, void* d_ws, size_t ws_size,
                              hipStream_t stream)
{
    const float* x     = (const float*)d_in[0];
    const float* qw    = (const float*)d_in[1];
    const float* kw    = (const float*)d_in[2];
    const float* vw    = (const float*)d_in[3];
    const float* pw    = (const float*)d_in[4];
    const float* pb    = (const float*)d_in[5];
    const float* gamma = (const float*)d_in[6];
    const float* beta  = (const float*)d_in[7];
    float* out = (float*)d_out;

    char* ws = (char*)d_ws;
    // Ao overlays xT (dead after K1); proj overlays Qt/Kt/Vn (dead after K2).
    unsigned short* xT = (unsigned short*)ws;                       //  9,437,184
    unsigned short* Ao = (unsigned short*)ws;                       //  overlay
    unsigned short* Wb = (unsigned short*)(ws + 9437184);           //    196,608
    unsigned short* Pb = (unsigned short*)(ws + 9633792);           //    131,072
    unsigned short* Qt = (unsigned short*)(ws + 9764864);           //  9,437,184
    unsigned short* Kt = (unsigned short*)(ws + 19202048);          //  2,359,296
    unsigned short* Vn = (unsigned short*)(ws + 21561344);          //  2,359,296
    float* proj  = (float*)(ws + 9764864);                          // 18,874,368 (overlay)
    float* stats = (float*)(ws + 28639232);                         //      2,048

    cvt_w_k<<<640, 256, 0, stream>>>(qw, kw, vw, pw, Wb, Pb);

    // batch = blockIdx.x everywhere -> round-robin pins batch b to XCD b,
    // keeping each batch's K/V resident in one XCD's L2.
    dim3 g0(BB, NN / 64, CCH / 64);
    cvt_x_k<<<g0, 256, 0, stream>>>(x, xT);

    dim3 g1(BB, NN / 64, 3);
    qkv_mfma_k<<<g1, 128, 0, stream>>>(Wb, xT, Qt, Kt, Vn);

    dim3 g2(BB, NN / 64, NH / 2);
    attn_k<<<g2, 256, 0, stream>>>(Qt, Kt, Vn, Ao);

    dim3 g3(BB, NN / 64, 2);
    proj_mfma_k<<<g3, 128, 0, stream>>>(Pb, Ao, pb, proj);

    bn_stats_k<<<CCH, 256, 0, stream>>>(proj, gamma, beta, stats);

    int total4 = BB * CCH * NN / 4;
    bn_apply_k<<<(total4 + 255) / 256, 256, 0, stream>>>(proj, x, stats, out);
}